// Round 1
// baseline (372.312 us; speedup 1.0000x reference)
//
#include <hip/hip_runtime.h>
#include <hip/hip_bf16.h>
#include <hip/hip_cooperative_groups.h>
#include <math.h>

namespace cg = cooperative_groups;

#define N_USERS 8192
#define DIMS    128
#define EDGES   262144
#define KCAND   131072
#define NTOT    (EDGES + KCAND)      // 393216
#define LISTCAP 131072
#define CAPB    512                  // per-block LDS staging capacity (entries)
#define NTILES  2080                 // triangular 64x64 tiles of 128x128
#define COS_THR 0.3f
#define EPS_SEL 6e-3f                // > hard error bound ~4e-3 of bf16 cos
#define LOGIT_MARGIN 2e-3f
#define DEADKEY 0xFFFFFFFFu

#define POST_BLOCKS 512
#define POST_GSZ    (POST_BLOCKS * 256)

typedef short bf16x8 __attribute__((ext_vector_type(8)));
typedef float f32x4  __attribute__((ext_vector_type(4)));

// u0 tiled layout: slab (i>>7) of 16384 shorts; within slab:
//   [cq = k>>3 (16)][row = i&127 (128)][k&7 (8)]
// -> each slab is 32 KB contiguous and byte-identical to the LDS As/Bs image.

// ---------------------------------------------------------------------------
// 1) prep (fused): blocks 0..31 -> normalize (bit-exact vs numpy) + tiled
//    bf16 copy + per-user partial logits; blocks 32..1055 -> excl bitmask.
// ---------------------------------------------------------------------------
__global__ __launch_bounds__(256) void prep_k(const float* __restrict__ x,
                                              const float* __restrict__ W,
                                              const int* __restrict__ nz,
                                              float* __restrict__ un,
                                              unsigned short* __restrict__ u0,
                                              float4* __restrict__ P,
                                              unsigned* __restrict__ excl) {
  if (blockIdx.x < 32) {
#pragma clang fp contract(off)
    int i = blockIdx.x * 256 + threadIdx.x;
    const float* r = x + (size_t)i * DIMS;
    float a[8];
#pragma unroll
    for (int j = 0; j < 8; ++j) { float t = r[j]; a[j] = t * t; }
    for (int b8 = 8; b8 < DIMS; b8 += 8) {
#pragma unroll
      for (int j = 0; j < 8; ++j) { float t = r[b8 + j]; a[j] = a[j] + t * t; }
    }
    float s = ((a[0] + a[1]) + (a[2] + a[3])) + ((a[4] + a[5]) + (a[6] + a[7]));
    float n = (float)sqrt((double)s);
    n = fmaxf(n, 1e-12f);
    // tiled bf16 emission: 16 coalesced uint4 stores (one per cq plane)
    unsigned short* slab = u0 + (size_t)(i >> 7) * 16384 + (i & 127) * 8;
#pragma unroll
    for (int cq = 0; cq < 16; ++cq) {
      unsigned short tmp[8];
#pragma unroll
      for (int t = 0; t < 8; ++t) {
        float v = r[cq * 8 + t] / n;
        un[(size_t)i * DIMS + cq * 8 + t] = v;
        __hip_bfloat16 h = __float2bfloat16(v);
        tmp[t] = *(unsigned short*)&h;
      }
      *(uint4*)(slab + (size_t)cq * 1024) = *(uint4*)tmp;
    }
    float a0 = 0.f, b0 = 0.f, a1 = 0.f, b1 = 0.f;
    for (int k = 0; k < DIMS; ++k) {
      float t = r[k];
      a0 = fmaf(t, W[k], a0);
      b0 = fmaf(t, W[128 + k], b0);
      a1 = fmaf(t, W[256 + k], a1);
      b1 = fmaf(t, W[384 + k], b1);
    }
    P[i] = make_float4(a0, b0, a1, b1);
  } else {
    int t = (blockIdx.x - 32) * 256 + threadIdx.x;
    if (t < EDGES) {
      int i = nz[2 * t], j = nz[2 * t + 1];
      atomicOr(&excl[(size_t)i * 256 + (j >> 5)], 1u << (j & 31));
    }
  }
}

// ---------------------------------------------------------------------------
// 2) mfma_pass: 128x128 tiles, triangular (bJ >= bI, 2080 independent blocks
//    of 512).  Single-shot K staging, ONE barrier.  u0 pre-tiled -> staging
//    loads are flat coalesced slab copies.  Wave tile 32x64, acc 32 VGPR.
//    Emit j>i + mirror; LDS list; ONE global atomicAdd per block.
//    (R0 of this session: unchanged — verified structure.)
// ---------------------------------------------------------------------------
__global__ __launch_bounds__(512) void mfma_pass(const unsigned short* __restrict__ u0,
                                                 uint2* __restrict__ list,
                                                 int* __restrict__ gcount) {
  __shared__ __align__(16) unsigned short As[4][4][128][8];  // 32 KB
  __shared__ __align__(16) unsigned short Bs[4][4][128][8];  // 32 KB
  __shared__ uint2 svec[CAPB];                               // 4 KB
  __shared__ int lcnt, lbase;

  const int tid  = threadIdx.x;
  const int lane = tid & 63;
  const int wv   = tid >> 6;
  const int quad = lane >> 4;
  const int l15  = lane & 15;

  // triangular decode: (bi, bj) with bj >= bi over 64 tiles of 128
  int rem = blockIdx.x, bi = 0;
  while (rem >= 64 - bi) { rem -= 64 - bi; ++bi; }
  const int bj = bi + rem;
  const int I0 = bi * 128, J0 = bj * 128;
  const int moff = (wv & 3) * 32, noff = (wv >> 2) * 64;

  if (tid == 0) lcnt = 0;

  // ---- single-shot staging: flat coalesced slab copy (memcpy semantics) ----
  const uint4* __restrict__ Aslab = (const uint4*)(u0 + (size_t)bi * 16384);
  const uint4* __restrict__ Bslab = (const uint4*)(u0 + (size_t)bj * 16384);
  uint4 pA[4], pB[4];
#pragma unroll
  for (int it = 0; it < 4; ++it) {
    pA[it] = Aslab[it * 512 + tid];
    pB[it] = Bslab[it * 512 + tid];
  }
#pragma unroll
  for (int it = 0; it < 4; ++it) {
    ((uint4*)As)[it * 512 + tid] = pA[it];
    ((uint4*)Bs)[it * 512 + tid] = pB[it];
  }
  __syncthreads();   // the ONLY barrier before the epilogue

  f32x4 acc[2][4];
#pragma unroll
  for (int mt = 0; mt < 2; ++mt)
#pragma unroll
    for (int nt = 0; nt < 4; ++nt)
#pragma unroll
      for (int g = 0; g < 4; ++g) acc[mt][nt][g] = 0.f;

  // ---- K loop: 4 kc x (2 af + 4 bfr b128 reads, 8 MFMAs), no barriers ----
#pragma unroll
  for (int kc = 0; kc < 4; ++kc) {
    bf16x8 af[2], bfr[4];
#pragma unroll
    for (int mt = 0; mt < 2; ++mt)
      af[mt] = *(const bf16x8*)&As[kc][quad][moff + mt * 16 + l15][0];
#pragma unroll
    for (int nt = 0; nt < 4; ++nt)
      bfr[nt] = *(const bf16x8*)&Bs[kc][quad][noff + nt * 16 + l15][0];
#pragma unroll
    for (int mt = 0; mt < 2; ++mt)
#pragma unroll
      for (int nt = 0; nt < 4; ++nt)
        acc[mt][nt] = __builtin_amdgcn_mfma_f32_16x16x32_bf16(
            af[mt], bfr[nt], acc[mt][nt], 0, 0, 0);
  }

  // ---- epilogue: j > i only; emit pair + mirror (one LDS atomic) ----
#pragma unroll
  for (int mt = 0; mt < 2; ++mt)
#pragma unroll
    for (int nt = 0; nt < 4; ++nt)
#pragma unroll
      for (int g = 0; g < 4; ++g) {
        float v = acc[mt][nt][g];
        if (v > COS_THR - EPS_SEL) {
          int i = I0 + moff + mt * 16 + quad * 4 + g;
          int j = J0 + noff + nt * 16 + l15;
          if (j > i) {
            int idx = atomicAdd(&lcnt, 2);
            if (idx + 1 < CAPB) {
              svec[idx]     = make_uint2(((unsigned)i << 13) | j,
                                         __float_as_uint(v));
              svec[idx + 1] = make_uint2(((unsigned)j << 13) | i,
                                         __float_as_uint(v));
            }
          }
        }
      }

  __syncthreads();
  int n = min(lcnt, CAPB);
  if (tid == 0) lbase = atomicAdd(gcount, n);
  __syncthreads();
  int base = lbase;
  for (int t = tid; t < n; t += 512) {
    int o = base + t;
    if (o < LISTCAP) list[o] = svec[t];
  }
}

// ---------------------------------------------------------------------------
// 3) post_k (cooperative, 512x256): the entire post-MFMA tail in ONE dispatch.
//    A: resolve + histogram   (was resolve_hist_k)
//    B: exclusive scan, block 0 only (was scan8k)
//    C: scatter (live entries only — padding is now derived in phase E)
//    D: per-row insertion sort by j (was sortrow_k)
//    E: finalize; pads (q >= M) emit (0,0,w=0) without touching cand arrays
//    grid.sync() between phases replaces 4 kernel-launch round-trips.
// ---------------------------------------------------------------------------
__global__ __launch_bounds__(256) void post_k(const float* __restrict__ un,
                                              const unsigned* __restrict__ excl,
                                              uint2* __restrict__ list,
                                              const int* __restrict__ gcount,
                                              int* __restrict__ row_cnt,
                                              int* __restrict__ row_off,
                                              int* __restrict__ row_pos,
                                              int* __restrict__ cand_i,
                                              int* __restrict__ cand_j,
                                              float* __restrict__ cand_v,
                                              const float* __restrict__ ue,
                                              const float* __restrict__ W,
                                              const float* __restrict__ b,
                                              const float* __restrict__ g,
                                              const int* __restrict__ nz,
                                              const float4* __restrict__ P,
                                              float* __restrict__ out) {
  cg::grid_group grid = cg::this_grid();
  const int gtid = blockIdx.x * 256 + threadIdx.x;

  // ---- A: resolve + histogram ----
  const int n = min(*gcount, LISTCAP);
  for (int t = gtid; t < n; t += POST_GSZ) {
    uint2 e = list[t];
    int i = e.x >> 13, j = e.x & 8191;
    unsigned word = excl[(size_t)i * 256 + (j >> 5)];
    bool alive = !(i == j || ((word >> (j & 31)) & 1u));
    float v = __uint_as_float(e.y);
    if (alive && v <= COS_THR + EPS_SEL) {   // borderline: decide exactly
      const float* a = un + (size_t)i * DIMS;
      const float* bb = un + (size_t)j * DIMS;
      float s = 0.f;
      for (int k = 0; k < DIMS; ++k) s = fmaf(a[k], bb[k], s);
      alive = (s > COS_THR);
      if (alive) list[t] = make_uint2(e.x, __float_as_uint(s));
    }
    if (!alive) list[t] = make_uint2(DEADKEY, 0u);
    else        atomicAdd(&row_cnt[i], 1);
  }
  grid.sync();

  // ---- B: exclusive scan over 8192 row counts (block 0 only) ----
  __shared__ int sm[256];
  if (blockIdx.x == 0) {
    int t = threadIdx.x;
    int base = t * 32;
    int s = 0;
    for (int i2 = 0; i2 < 32; ++i2) s += row_cnt[base + i2];
    sm[t] = s;
    __syncthreads();
    int x = s;
    for (int d = 1; d < 256; d <<= 1) {
      int y = (t >= d) ? sm[t - d] : 0;
      __syncthreads();
      x += y;
      sm[t] = x;
      __syncthreads();
    }
    int run = x - s;
    for (int i2 = 0; i2 < 32; ++i2) {
      row_off[base + i2] = run;
      run += row_cnt[base + i2];
    }
    if (t == 255) row_off[N_USERS] = x;
  }
  grid.sync();

  // ---- C: scatter live entries ----
  for (int t = gtid; t < n; t += POST_GSZ) {
    uint2 e = list[t];
    if (e.x != DEADKEY) {
      int i = e.x >> 13, j = e.x & 8191;
      int pos = row_off[i] + atomicAdd(&row_pos[i], 1);
      if (pos < KCAND) {
        cand_i[pos] = i;
        cand_j[pos] = j;
        cand_v[pos] = __uint_as_float(e.y);
      }
    }
  }
  grid.sync();

  // ---- D: per-row insertion sort ascending by j ----
  for (int r = gtid; r < N_USERS; r += POST_GSZ) {
    int o = row_off[r], c = row_cnt[r];
    if (o + c > KCAND) c = max(0, KCAND - o);
    for (int a = 1; a < c; ++a) {
      int jv = cand_j[o + a];
      float vv = cand_v[o + a];
      int bq = a - 1;
      while (bq >= 0 && cand_j[o + bq] > jv) {
        cand_j[o + bq + 1] = cand_j[o + bq];
        cand_v[o + bq + 1] = cand_v[o + bq];
        --bq;
      }
      cand_j[o + bq + 1] = jv;
      cand_v[o + bq + 1] = vv;
    }
  }
  grid.sync();

  // ---- E: finalize (pads derived from M, no cand reads, no pad stores) ----
  const int M = row_off[N_USERS];
  for (int p = gtid; p < NTOT; p += POST_GSZ) {
    int i, j;
    float wgt;
    if (p < EDGES) {
      i = nz[2 * p];
      j = nz[2 * p + 1];
      wgt = 1.0f;
    } else {
      int q = p - EDGES;
      if (q >= M) {
        // reference pad: pair (0,0), weight max(cos[0,0]=-1, 0) = 0
        out[p] = 0.0f;
        out[NTOT + p] = 0.0f;
        out[2 * NTOT + p] = 0.0f;
        out[3 * NTOT + 2 * p + 0] = 0.0f;
        out[3 * NTOT + 2 * p + 1] = 0.0f;
        continue;
      }
      i = cand_i[q];
      j = cand_j[q];
      wgt = fmaxf(cand_v[q], 0.0f);
    }

    float4 Pi = P[i], Pj = P[j];
    float l0 = Pi.x + Pj.y + b[0];
    float l1 = Pi.z + Pj.w + b[1];
    float g0 = g[2 * p], g1 = g[2 * p + 1];
    float s0 = l0 + g0, s1 = l1 + g1;

    if (fabsf(s0 - s1) < LOGIT_MARGIN) {
      const float* ri = ue + (size_t)i * DIMS;
      const float* rj = ue + (size_t)j * DIMS;
      float e0 = 0.f, e1 = 0.f;
      for (int k = 0; k < DIMS; ++k) {
        e0 = fmaf(ri[k], W[k], e0);
        e1 = fmaf(ri[k], W[256 + k], e1);
      }
      for (int k = 0; k < DIMS; ++k) {
        e0 = fmaf(rj[k], W[128 + k], e0);
        e1 = fmaf(rj[k], W[384 + k], e1);
      }
      s0 = (e0 + b[0]) + g0;
      s1 = (e1 + b[1]) + g1;
    }

    float w = (s0 >= s1) ? wgt : 0.0f;

    out[p] = w;
    out[NTOT + p] = w;
    out[2 * NTOT + p] = w;
    out[3 * NTOT + 2 * p + 0] = (float)i;
    out[3 * NTOT + 2 * p + 1] = (float)j;
  }
}

// ---------------------------------------------------------------------------
extern "C" void kernel_launch(void* const* d_in, const int* in_sizes, int n_in,
                              void* d_out, int out_size, void* d_ws, size_t ws_size,
                              hipStream_t stream) {
  (void)in_sizes; (void)n_in; (void)out_size; (void)ws_size;

  const float* user_emb = (const float*)d_in[0];
  const float* W        = (const float*)d_in[1];
  const float* b        = (const float*)d_in[2];
  const float* gnoise   = (const float*)d_in[3];
  const int*   nz       = (const int*)d_in[4];
  float* out = (float*)d_out;

  char* ws = (char*)d_ws;
  float*          un      = (float*)(ws + 0);                        // 4 MB
  unsigned short* u0      = (unsigned short*)(ws + (4u << 20));      // 2 MB (tiled)
  unsigned*       excl    = (unsigned*)(ws + (6u << 20));            // 8 MB
  // zeroed region directly after excl: gcount | row_cnt | row_pos
  char*           zbase   = ws + (14u << 20);
  int*            gcount  = (int*)(zbase);                           // 64 B slot
  int*            row_cnt = (int*)(zbase + 64);                      // 32 KB
  int*            row_pos = (int*)(zbase + 64 + 32768);              // 32 KB
  int*            row_off = (int*)(ws + (14u << 20) + (96u << 10));  // 32.8 KB
  uint2*          list    = (uint2*)(ws + (15u << 20));              // 1 MB
  int*            cand_i  = (int*)(ws + (16u << 20));                // 512 KB
  int*            cand_j  = (int*)(ws + (16u << 20) + (512u << 10)); // 512 KB
  float*          cand_v  = (float*)(ws + (17u << 20));              // 512 KB
  float4*         P       = (float4*)(ws + (17u << 20) + (512u << 10)); // 128 KB

  // one memset: excl (8 MB) + counter region (96 KB) are contiguous
  hipMemsetAsync(excl, 0, (8u << 20) + (96u << 10), stream);

  prep_k<<<32 + EDGES / 256, 256, 0, stream>>>(user_emb, W, nz, un, u0, P, excl);
  mfma_pass<<<NTILES, 512, 0, stream>>>(u0, list, gcount);

  // fused cooperative tail: resolve -> scan -> scatter -> sort -> finalize
  const float* un_c   = un;
  const unsigned* excl_c = excl;
  uint2* list_c       = list;
  const int* gcount_c = gcount;
  int* row_cnt_c      = row_cnt;
  int* row_off_c      = row_off;
  int* row_pos_c      = row_pos;
  int* cand_i_c       = cand_i;
  int* cand_j_c       = cand_j;
  float* cand_v_c     = cand_v;
  const float* ue_c   = user_emb;
  const float* W_c    = W;
  const float* b_c    = b;
  const float* g_c    = gnoise;
  const int* nz_c     = nz;
  const float4* P_c   = P;
  float* out_c        = out;
  void* args[] = {&un_c, &excl_c, &list_c, &gcount_c, &row_cnt_c, &row_off_c,
                  &row_pos_c, &cand_i_c, &cand_j_c, &cand_v_c, &ue_c, &W_c,
                  &b_c, &g_c, &nz_c, &P_c, &out_c};
  hipLaunchCooperativeKernel((void*)post_k, dim3(POST_BLOCKS), dim3(256),
                             args, 0, stream);
}

// Round 2
// 151.711 us; speedup vs baseline: 2.4541x; 2.4541x over previous
//
#include <hip/hip_runtime.h>
#include <hip/hip_bf16.h>
#include <math.h>

#define N_USERS 8192
#define DIMS    128
#define EDGES   262144
#define KCAND   131072
#define NTOT    (EDGES + KCAND)      // 393216
#define LISTCAP 131072
#define CAPB    512                  // per-block LDS staging capacity (entries)
#define NTILES  2080                 // triangular 64x64 tiles of 128x128
#define COS_THR 0.3f
#define EPS_SEL 6e-3f                // > hard error bound ~4e-3 of bf16 cos
#define LOGIT_MARGIN 2e-3f

typedef short bf16x8 __attribute__((ext_vector_type(8)));
typedef float f32x4  __attribute__((ext_vector_type(4)));

// u0 tiled layout: slab (i>>7) of 16384 shorts; within slab:
//   [cq = k>>3 (16)][row = i&127 (128)][k&7 (8)]
// -> each slab is 32 KB contiguous and byte-identical to the LDS As/Bs image.

// ---------------------------------------------------------------------------
// 1) prep (R2 rewrite): blocks 0..255 -> normalize with 8 THREADS PER ROW
//    (was 1 thread/row with 128 scalar strided loads = 64 lines/wave-instr).
//    Thread j of a row owns elements k%8==j: loads are 32B-contiguous per
//    8-lane group; the per-j square accumulation + shfl_xor(1,2,4) tree
//    reproduces the reference sum order BIT-EXACTLY (commutativity only),
//    so un/u0 bytes are identical to the verified R0 kernel.
//    u0 stores: lane-linear -> 128B contiguous per wave (perfect).
//    P partial-dot reduced via shfl tree (ordering slack covered by the
//    LOGIT_MARGIN exact-chain fallback in finalize).
//    Blocks 256..1279 -> excl bitmask (unchanged).
// ---------------------------------------------------------------------------
__global__ __launch_bounds__(256) void prep_k(const float* __restrict__ x,
                                              const float* __restrict__ W,
                                              const int* __restrict__ nz,
                                              float* __restrict__ un,
                                              unsigned short* __restrict__ u0,
                                              float4* __restrict__ P,
                                              unsigned* __restrict__ excl) {
  if (blockIdx.x < 256) {
#pragma clang fp contract(off)
    const int tid  = threadIdx.x;
    const int rloc = tid >> 3;          // 0..31 rows per block
    const int j    = tid & 7;           // element class k%8
    const int i    = blockIdx.x * 32 + rloc;
    const float* r = x + (size_t)i * DIMS;

    float vals[16];
    float a = 0.f;
#pragma unroll
    for (int b8 = 0; b8 < 16; ++b8) {
      float t = r[b8 * 8 + j];
      vals[b8] = t;
      a = a + t * t;                    // exact a[j] of the reference chain
    }
    // s = ((a0+a1)+(a2+a3)) + ((a4+a5)+(a6+a7)) — xor tree matches exactly
    a = a + __shfl_xor(a, 1, 64);
    a = a + __shfl_xor(a, 2, 64);
    float s = a + __shfl_xor(a, 4, 64);
    float n = (float)sqrt((double)s);
    n = fmaxf(n, 1e-12f);

    unsigned short* slab = u0 + (size_t)(i >> 7) * 16384 + (i & 127) * 8;
    float p0 = 0.f, p1 = 0.f, p2 = 0.f, p3 = 0.f;
#pragma unroll
    for (int b8 = 0; b8 < 16; ++b8) {
      int k = b8 * 8 + j;
      float t = vals[b8];
      float v = t / n;
      un[(size_t)i * DIMS + k] = v;
      __hip_bfloat16 h = __float2bfloat16(v);
      slab[(size_t)b8 * 1024 + j] = *(unsigned short*)&h;
      p0 = fmaf(t, W[k], p0);
      p1 = fmaf(t, W[128 + k], p1);
      p2 = fmaf(t, W[256 + k], p2);
      p3 = fmaf(t, W[384 + k], p3);
    }
#pragma unroll
    for (int m = 1; m < 8; m <<= 1) {
      p0 += __shfl_xor(p0, m, 64);
      p1 += __shfl_xor(p1, m, 64);
      p2 += __shfl_xor(p2, m, 64);
      p3 += __shfl_xor(p3, m, 64);
    }
    if (j == 0) P[i] = make_float4(p0, p1, p2, p3);
  } else {
    int t = (blockIdx.x - 256) * 256 + threadIdx.x;
    if (t < EDGES) {
      int i = nz[2 * t], j = nz[2 * t + 1];
      atomicOr(&excl[(size_t)i * 256 + (j >> 5)], 1u << (j & 31));
    }
  }
}

// ---------------------------------------------------------------------------
// 2) mfma_pass (R2: resolve+histogram FUSED into the epilogue).
//    128x128 tiles, triangular, single-shot flat slab staging, ONE barrier,
//    wave tile 32x64, acc 32 VGPR — all verified structure, unchanged.
//    Epilogue now: j>i candidates are exclusion-checked (both directions,
//    excl is complete after prep) and borderline values are resolved exactly
//    via un before pushing — list contains ONLY live entries, row_cnt is
//    built here, and the old resolve_hist_k dispatch disappears.
// ---------------------------------------------------------------------------
__global__ __launch_bounds__(512) void mfma_pass(const unsigned short* __restrict__ u0,
                                                 const float* __restrict__ un,
                                                 const unsigned* __restrict__ excl,
                                                 uint2* __restrict__ list,
                                                 int* __restrict__ gcount,
                                                 int* __restrict__ row_cnt) {
  __shared__ __align__(16) unsigned short As[4][4][128][8];  // 32 KB
  __shared__ __align__(16) unsigned short Bs[4][4][128][8];  // 32 KB
  __shared__ uint2 svec[CAPB];                               // 4 KB
  __shared__ int lcnt, lbase;

  const int tid  = threadIdx.x;
  const int lane = tid & 63;
  const int wv   = tid >> 6;
  const int quad = lane >> 4;
  const int l15  = lane & 15;

  // triangular decode: (bi, bj) with bj >= bi over 64 tiles of 128
  int rem = blockIdx.x, bi = 0;
  while (rem >= 64 - bi) { rem -= 64 - bi; ++bi; }
  const int bj = bi + rem;
  const int I0 = bi * 128, J0 = bj * 128;
  const int moff = (wv & 3) * 32, noff = (wv >> 2) * 64;

  if (tid == 0) lcnt = 0;

  // ---- single-shot staging: flat coalesced slab copy (memcpy semantics) ----
  const uint4* __restrict__ Aslab = (const uint4*)(u0 + (size_t)bi * 16384);
  const uint4* __restrict__ Bslab = (const uint4*)(u0 + (size_t)bj * 16384);
  uint4 pA[4], pB[4];
#pragma unroll
  for (int it = 0; it < 4; ++it) {
    pA[it] = Aslab[it * 512 + tid];
    pB[it] = Bslab[it * 512 + tid];
  }
#pragma unroll
  for (int it = 0; it < 4; ++it) {
    ((uint4*)As)[it * 512 + tid] = pA[it];
    ((uint4*)Bs)[it * 512 + tid] = pB[it];
  }
  __syncthreads();   // the ONLY barrier before the epilogue

  f32x4 acc[2][4];
#pragma unroll
  for (int mt = 0; mt < 2; ++mt)
#pragma unroll
    for (int nt = 0; nt < 4; ++nt)
#pragma unroll
      for (int g = 0; g < 4; ++g) acc[mt][nt][g] = 0.f;

  // ---- K loop: 4 kc x (2 af + 4 bfr b128 reads, 8 MFMAs), no barriers ----
#pragma unroll
  for (int kc = 0; kc < 4; ++kc) {
    bf16x8 af[2], bfr[4];
#pragma unroll
    for (int mt = 0; mt < 2; ++mt)
      af[mt] = *(const bf16x8*)&As[kc][quad][moff + mt * 16 + l15][0];
#pragma unroll
    for (int nt = 0; nt < 4; ++nt)
      bfr[nt] = *(const bf16x8*)&Bs[kc][quad][noff + nt * 16 + l15][0];
#pragma unroll
    for (int mt = 0; mt < 2; ++mt)
#pragma unroll
      for (int nt = 0; nt < 4; ++nt)
        acc[mt][nt] = __builtin_amdgcn_mfma_f32_16x16x32_bf16(
            af[mt], bfr[nt], acc[mt][nt], 0, 0, 0);
  }

  // ---- epilogue: j>i; resolve (excl both dirs + borderline exact) inline ---
#pragma unroll
  for (int mt = 0; mt < 2; ++mt)
#pragma unroll
    for (int nt = 0; nt < 4; ++nt)
#pragma unroll
      for (int g = 0; g < 4; ++g) {
        float v = acc[mt][nt][g];
        if (v > COS_THR - EPS_SEL) {
          int i = I0 + moff + mt * 16 + quad * 4 + g;
          int j = J0 + noff + nt * 16 + l15;
          if (j > i) {
            float vv = v;
            bool pass = true;
            if (v <= COS_THR + EPS_SEL) {   // borderline: decide exactly
              const float* a = un + (size_t)i * DIMS;
              const float* bb = un + (size_t)j * DIMS;
              float s2 = 0.f;
              for (int k = 0; k < DIMS; ++k) s2 = fmaf(a[k], bb[k], s2);
              pass = (s2 > COS_THR);
              vv = s2;
            }
            if (pass) {
              unsigned wij = excl[(size_t)i * 256 + (j >> 5)];
              unsigned wji = excl[(size_t)j * 256 + (i >> 5)];
              unsigned uvv = __float_as_uint(vv);
              if (!((wij >> (j & 31)) & 1u)) {
                int idx = atomicAdd(&lcnt, 1);
                if (idx < CAPB) {
                  svec[idx] = make_uint2(((unsigned)i << 13) | j, uvv);
                  atomicAdd(&row_cnt[i], 1);
                }
              }
              if (!((wji >> (i & 31)) & 1u)) {
                int idx = atomicAdd(&lcnt, 1);
                if (idx < CAPB) {
                  svec[idx] = make_uint2(((unsigned)j << 13) | i, uvv);
                  atomicAdd(&row_cnt[j], 1);
                }
              }
            }
          }
        }
      }

  __syncthreads();
  int n = min(lcnt, CAPB);
  if (tid == 0) lbase = atomicAdd(gcount, n);
  __syncthreads();
  int base = lbase;
  for (int t = tid; t < n; t += 512) {
    int o = base + t;
    if (o < LISTCAP) list[o] = svec[t];
  }
}

// 3) exclusive scan over 8192 row counts (single block)
__global__ __launch_bounds__(256) void scan8k(const int* __restrict__ cnt,
                                              int* __restrict__ off) {
  __shared__ int sm[256];
  int t = threadIdx.x;
  int base = t * 32;
  int s = 0;
  for (int i = 0; i < 32; ++i) s += cnt[base + i];
  sm[t] = s;
  __syncthreads();
  int x = s;
  for (int d = 1; d < 256; d <<= 1) {
    int y = (t >= d) ? sm[t - d] : 0;
    __syncthreads();
    x += y;
    sm[t] = x;
    __syncthreads();
  }
  int run = x - s;
  for (int i = 0; i < 32; ++i) { off[base + i] = run; run += cnt[base + i]; }
  if (t == 255) off[N_USERS] = x;
}

// 4) scatter (R2: list is all-live, no DEADKEY, no pad writes — pads are
//    derived in finalize from M)
__global__ __launch_bounds__(256) void scatter_k(const uint2* __restrict__ list,
                                                 const int* __restrict__ gcount,
                                                 const int* __restrict__ row_off,
                                                 int* __restrict__ row_pos,
                                                 int* __restrict__ cand_i,
                                                 int* __restrict__ cand_j,
                                                 float* __restrict__ cand_v) {
  int t = blockIdx.x * 256 + threadIdx.x;
  int n = min(*gcount, LISTCAP);
  if (t >= n) return;
  uint2 e = list[t];
  int i = e.x >> 13, j = e.x & 8191;
  int pos = row_off[i] + atomicAdd(&row_pos[i], 1);
  if (pos < KCAND) {
    cand_i[pos] = i;
    cand_j[pos] = j;
    cand_v[pos] = __uint_as_float(e.y);
  }
}

// 5) sort each row's span ascending by j
__global__ __launch_bounds__(256) void sortrow_k(const int* __restrict__ row_off,
                                                 const int* __restrict__ row_cnt,
                                                 int* __restrict__ cand_j,
                                                 float* __restrict__ cand_v) {
  int r = blockIdx.x * 256 + threadIdx.x;
  if (r >= N_USERS) return;
  int o = row_off[r], c = row_cnt[r];
  if (o + c > KCAND) c = max(0, KCAND - o);
  for (int a = 1; a < c; ++a) {
    int jv = cand_j[o + a];
    float vv = cand_v[o + a];
    int b = a - 1;
    while (b >= 0 && cand_j[o + b] > jv) {
      cand_j[o + b + 1] = cand_j[o + b];
      cand_v[o + b + 1] = cand_v[o + b];
      --b;
    }
    cand_j[o + b + 1] = jv;
    cand_v[o + b + 1] = vv;
  }
}

// 6) finalize (split logits + exact-chain fallback near ties; pads q>=M
//    emit (0,0,w=0) directly — validated in R1)
__global__ __launch_bounds__(256) void finalize_k(const float* __restrict__ ue,
                                                  const float* __restrict__ W,
                                                  const float* __restrict__ b,
                                                  const float* __restrict__ g,
                                                  const int* __restrict__ nz,
                                                  const int* __restrict__ cand_i,
                                                  const int* __restrict__ cand_j,
                                                  const float* __restrict__ cand_v,
                                                  const int* __restrict__ row_off,
                                                  const float4* __restrict__ P,
                                                  float* __restrict__ out) {
  int p = blockIdx.x * 256 + threadIdx.x;
  if (p >= NTOT) return;

  int i, j;
  float wgt;
  if (p < EDGES) {
    i = nz[2 * p];
    j = nz[2 * p + 1];
    wgt = 1.0f;
  } else {
    int q = p - EDGES;
    if (q >= row_off[N_USERS]) {
      // reference pad: pair (0,0), weight max(cos[0,0]=-1, 0) = 0
      out[p] = 0.0f;
      out[NTOT + p] = 0.0f;
      out[2 * NTOT + p] = 0.0f;
      out[3 * NTOT + 2 * p + 0] = 0.0f;
      out[3 * NTOT + 2 * p + 1] = 0.0f;
      return;
    }
    i = cand_i[q];
    j = cand_j[q];
    wgt = fmaxf(cand_v[q], 0.0f);
  }

  float4 Pi = P[i], Pj = P[j];
  float l0 = Pi.x + Pj.y + b[0];
  float l1 = Pi.z + Pj.w + b[1];
  float g0 = g[2 * p], g1 = g[2 * p + 1];
  float s0 = l0 + g0, s1 = l1 + g1;

  if (fabsf(s0 - s1) < LOGIT_MARGIN) {
    const float* ri = ue + (size_t)i * DIMS;
    const float* rj = ue + (size_t)j * DIMS;
    float e0 = 0.f, e1 = 0.f;
    for (int k = 0; k < DIMS; ++k) {
      e0 = fmaf(ri[k], W[k], e0);
      e1 = fmaf(ri[k], W[256 + k], e1);
    }
    for (int k = 0; k < DIMS; ++k) {
      e0 = fmaf(rj[k], W[128 + k], e0);
      e1 = fmaf(rj[k], W[384 + k], e1);
    }
    s0 = (e0 + b[0]) + g0;
    s1 = (e1 + b[1]) + g1;
  }

  float w = (s0 >= s1) ? wgt : 0.0f;

  out[p] = w;
  out[NTOT + p] = w;
  out[2 * NTOT + p] = w;
  out[3 * NTOT + 2 * p + 0] = (float)i;
  out[3 * NTOT + 2 * p + 1] = (float)j;
}

// ---------------------------------------------------------------------------
extern "C" void kernel_launch(void* const* d_in, const int* in_sizes, int n_in,
                              void* d_out, int out_size, void* d_ws, size_t ws_size,
                              hipStream_t stream) {
  (void)in_sizes; (void)n_in; (void)out_size; (void)ws_size;

  const float* user_emb = (const float*)d_in[0];
  const float* W        = (const float*)d_in[1];
  const float* b        = (const float*)d_in[2];
  const float* gnoise   = (const float*)d_in[3];
  const int*   nz       = (const int*)d_in[4];
  float* out = (float*)d_out;

  char* ws = (char*)d_ws;
  float*          un      = (float*)(ws + 0);                        // 4 MB
  unsigned short* u0      = (unsigned short*)(ws + (4u << 20));      // 2 MB (tiled)
  unsigned*       excl    = (unsigned*)(ws + (6u << 20));            // 8 MB
  // zeroed region directly after excl: gcount | row_cnt | row_pos
  char*           zbase   = ws + (14u << 20);
  int*            gcount  = (int*)(zbase);                           // 64 B slot
  int*            row_cnt = (int*)(zbase + 64);                      // 32 KB
  int*            row_pos = (int*)(zbase + 64 + 32768);              // 32 KB
  int*            row_off = (int*)(ws + (14u << 20) + (96u << 10));  // 32.8 KB
  uint2*          list    = (uint2*)(ws + (15u << 20));              // 1 MB
  int*            cand_i  = (int*)(ws + (16u << 20));                // 512 KB
  int*            cand_j  = (int*)(ws + (16u << 20) + (512u << 10)); // 512 KB
  float*          cand_v  = (float*)(ws + (17u << 20));              // 512 KB
  float4*         P       = (float4*)(ws + (17u << 20) + (512u << 10)); // 128 KB

  // one memset: excl (8 MB) + counter region (96 KB) are contiguous
  hipMemsetAsync(excl, 0, (8u << 20) + (96u << 10), stream);

  prep_k<<<256 + EDGES / 256, 256, 0, stream>>>(user_emb, W, nz, un, u0, P, excl);
  mfma_pass<<<NTILES, 512, 0, stream>>>(u0, un, excl, list, gcount, row_cnt);
  scan8k<<<1, 256, 0, stream>>>(row_cnt, row_off);
  scatter_k<<<LISTCAP / 256, 256, 0, stream>>>(list, gcount, row_off, row_pos,
                                               cand_i, cand_j, cand_v);
  sortrow_k<<<N_USERS / 256, 256, 0, stream>>>(row_off, row_cnt, cand_j, cand_v);
  finalize_k<<<NTOT / 256, 256, 0, stream>>>(user_emb, W, b, gnoise, nz,
                                             cand_i, cand_j, cand_v, row_off,
                                             P, out);
}